// Round 14
// baseline (167.008 us; speedup 1.0000x reference)
//
#include <hip/hip_runtime.h>
#include <hip/hip_bf16.h>

#define N_NODES 20000
#define E_EDGES 320000
#define NH 8
#define NC 32
#define HC 256
#define FIN 41
#define NG 64
#define PCHUNK 16
#define NPAD 20032

typedef _Float16 f16x4 __attribute__((ext_vector_type(4)));
typedef _Float16 f16x8 __attribute__((ext_vector_type(8)));
typedef float f32x4v __attribute__((ext_vector_type(4)));

// ---------------- CSR build ----------------
// cnt[] holds EDGE counts only (zeroed by memset); row size = cnt[n] + 1 (self loop).

__global__ __launch_bounds__(256) void hist(const int* __restrict__ ei, int* cnt) {
    int e = blockIdx.x * 256 + threadIdx.x;
    if (e < E_EDGES) atomicAdd(&cnt[ei[E_EDGES + e]], 1);
}

__global__ __launch_bounds__(512) void scanA(const int* __restrict__ cnt, int* partial) {
    __shared__ int red[512];
    int n = blockIdx.x * 512 + threadIdx.x;
    int v = (n < N_NODES) ? cnt[n] + 1 : 0;
    red[threadIdx.x] = v; __syncthreads();
    for (int off = 256; off > 0; off >>= 1) {
        if (threadIdx.x < off) red[threadIdx.x] += red[threadIdx.x + off];
        __syncthreads();
    }
    if (threadIdx.x == 0) partial[blockIdx.x] = red[0];
}

// scanC with inlined cross-block prefix (first wave shfl-scans the 40 partials)
__global__ __launch_bounds__(512) void scanC(const int* __restrict__ cnt, const int* __restrict__ partial,
                                             int* row_ptr, int* cursor, int* colidx) {
    __shared__ int buf[512];
    __shared__ int pbase;
    int t = threadIdx.x;
    if (t < 64) {
        int v = (t < 40) ? partial[t] : 0;
        int own = v;
        for (int off = 1; off < 64; off <<= 1) {
            int y = __shfl_up(v, off);
            if (t >= off) v += y;
        }
        if (t == (int)blockIdx.x) pbase = v - own;  // exclusive prefix at blockIdx.x
    }
    int n = blockIdx.x * 512 + t;
    int v = (n < N_NODES) ? cnt[n] + 1 : 0;
    int x = v;
    buf[t] = x; __syncthreads();
    for (int off = 1; off < 512; off <<= 1) {
        int y = (t >= off) ? buf[t - off] : 0;
        __syncthreads();
        x += y; buf[t] = x; __syncthreads();
    }
    int excl = pbase + x - v;
    if (n < N_NODES) {
        row_ptr[n] = excl;
        cursor[n] = excl + 1;     // self loop occupies slot 0
        colidx[excl] = n;         // self loop
    }
    if (n == 0) row_ptr[N_NODES] = E_EDGES + N_NODES;
}

__global__ __launch_bounds__(256) void fill_csr(const int* __restrict__ ei, int* cursor, int* colidx) {
    int e = blockIdx.x * 256 + threadIdx.x;
    if (e >= E_EDGES) return;
    int d = ei[E_EDGES + e];
    int s = ei[e];
    int pos = atomicAdd(&cursor[d], 1);
    colidx[pos] = s;
}

// ---------------- prep ----------------
// blocks 0..15:    W2 -> fp16 col-major Wt[256][256]
// blocks 16..144:  fc1w -> fc1wT[64][520]
// blocks 145..223: graph_ranges
// blocks 224..287: W1 [41][256] -> fp16 col-major W1t[256][64] (zero-padded K)
// blocks 288..913: x [20000][41] -> fp16 xpad[20032][64] (zero-padded)

__global__ __launch_bounds__(256) void prep(const float* __restrict__ W, _Float16* __restrict__ Wt,
                                            const float* __restrict__ fc1w, float* __restrict__ fc1wT,
                                            const int* __restrict__ batch, int* gstart, int* gend,
                                            const float* __restrict__ W1, _Float16* __restrict__ W1t,
                                            const float* __restrict__ x, _Float16* __restrict__ xpad) {
    __shared__ float tile[64][65];
    int b = blockIdx.x;
    int t = threadIdx.x;
    if (b < 16) {
        int tr = (b >> 2) * 64;
        int tc = (b & 3) * 64;
        int rr = t >> 6, cc = t & 63;
#pragma unroll
        for (int j = 0; j < 16; ++j) {
            int row = j * 4 + rr;
            tile[row][cc] = W[(size_t)(tr + row) * 256 + tc + cc];
        }
        __syncthreads();
#pragma unroll
        for (int j = 0; j < 16; ++j) {
            int row = j * 4 + rr;
            Wt[(size_t)(tc + row) * 256 + tr + cc] = (_Float16)tile[cc][row];
        }
    } else if (b < 145) {
        int id = (b - 16) * 256 + t;
        if (id < 64 * 514) {
            int u = id / 514, kk = id - u * 514;
            fc1wT[u * 520 + kk] = fc1w[kk * 64 + u];
        }
    } else if (b < 224) {
        int n = (b - 145) * 256 + t;
        if (n < N_NODES) {
            int bb = batch[n];
            if (n == 0) gstart[bb] = 0;
            else {
                int pb = batch[n - 1];
                if (pb != bb) { gstart[bb] = n; gend[pb] = n; }
            }
            if (n == N_NODES - 1) gend[bb] = N_NODES;
        }
    } else if (b < 288) {
        int id = (b - 224) * 256 + t;       // 16384 = 256 cols x 64 K
        int n = id >> 6, k = id & 63;
        W1t[id] = (k < FIN) ? (_Float16)W1[k * 256 + n] : (_Float16)0.f;
    } else {
        int row = (b - 288) * 32 + (t >> 3);
        int c8 = (t & 7) * 8;
        f16x8 v;
#pragma unroll
        for (int j = 0; j < 8; ++j) {
            int c = c8 + j;
            float f = (row < N_NODES && c < FIN) ? x[(size_t)row * FIN + c] : 0.f;
            v[j] = (_Float16)f;
        }
        if (row < NPAD) *(f16x8*)(xpad + (size_t)row * 64 + c8) = v;
    }
}

// ---------------- GEMM K=256 via MFMA fp16 (16x16x32), B-in-LDS, 64x128 blocks ----------------
// block = 64 rows x 128 cols (4 heads); grid = 313*2 = 626; 2 blocks/CU (69.6 KB LDS).
// A-traffic duplication 2x (was 8x). Output-transpose buffer aliases bs after sync.

__global__ __launch_bounds__(256) void gemm256h(const _Float16* __restrict__ Xh,
                                                const _Float16* __restrict__ Wt,
                                                const float* __restrict__ a_src,
                                                const float* __restrict__ a_dst,
                                                _Float16* __restrict__ Hh,
                                                float* __restrict__ ssrc,
                                                float* __restrict__ sdst) {
    __shared__ _Float16 bs[128 * 272];          // 69.6 KB; reused as hs[64*136] after compute
    int row0 = (blockIdx.x >> 1) * 64;
    int half = blockIdx.x & 1;
    int c0 = half * 128;
    int tid = threadIdx.x;
    int lane = tid & 63;
    int v = tid >> 6;
    int r16 = lane & 15;
    int kseg = lane >> 4;

    // stage B: 128 cols x 256 K = 4096 chunks of 8 halfs, 16/thread, coalesced
#pragma unroll
    for (int i = 0; i < 16; ++i) {
        int chunk = i * 256 + tid;
        int c = chunk >> 5;
        int k = (chunk & 31) * 8;
        f16x8 xv = *(const f16x8*)(Wt + (size_t)(c0 + c) * 256 + k);
        *(f16x8*)(&bs[c * 272 + k]) = xv;
    }

    // A-frags: all 8 K-steps for this wave's 16 rows
    int arow = row0 + v * 16 + r16;
    const _Float16* XA = Xh + (size_t)arow * 256 + kseg * 8;
    f16x8 af[8];
#pragma unroll
    for (int s = 0; s < 8; ++s) af[s] = *(const f16x8*)(XA + s * 32);

    __syncthreads();

    f32x4v acc[8];
#pragma unroll
    for (int tn = 0; tn < 8; ++tn) acc[tn] = (f32x4v){0.f, 0.f, 0.f, 0.f};

#pragma unroll
    for (int tn = 0; tn < 8; ++tn) {
        f16x8 bf[8];
#pragma unroll
        for (int s = 0; s < 8; ++s)
            bf[s] = *(const f16x8*)(&bs[(tn * 16 + r16) * 272 + kseg * 8 + s * 32]);
#pragma unroll
        for (int s = 0; s < 8; ++s)
            acc[tn] = __builtin_amdgcn_mfma_f32_16x16x32_f16(af[s], bf[s], acc[tn], 0, 0, 0);
    }

    // fused score dots: 4 heads in this half; head hh = cols [c0+hh*32, +32) = tn 2hh,2hh+1
#pragma unroll
    for (int hh = 0; hh < 4; ++hh) {
        float as0 = a_src[c0 + hh * 32 + r16], as1 = a_src[c0 + hh * 32 + 16 + r16];
        float ad0 = a_dst[c0 + hh * 32 + r16], ad1 = a_dst[c0 + hh * 32 + 16 + r16];
#pragma unroll
        for (int r = 0; r < 4; ++r) {
            float p = acc[2 * hh][r] * as0 + acc[2 * hh + 1][r] * as1;
            float q = acc[2 * hh][r] * ad0 + acc[2 * hh + 1][r] * ad1;
            p += __shfl_xor(p, 1); q += __shfl_xor(q, 1);
            p += __shfl_xor(p, 2); q += __shfl_xor(q, 2);
            p += __shfl_xor(p, 4); q += __shfl_xor(q, 4);
            p += __shfl_xor(p, 8); q += __shfl_xor(q, 8);
            int row = row0 + v * 16 + kseg * 4 + r;
            if (r16 == 0 && row < N_NODES) {
                ssrc[row * NH + half * 4 + hh] = p;
                sdst[row * NH + half * 4 + hh] = q;
            }
        }
    }

    // H (fp16) via LDS transpose (reuse bs)
    __syncthreads();
    _Float16* hs = bs;
#pragma unroll
    for (int tn = 0; tn < 8; ++tn)
#pragma unroll
        for (int r = 0; r < 4; ++r)
            hs[(v * 16 + kseg * 4 + r) * 136 + tn * 16 + r16] = (_Float16)acc[tn][r];
    __syncthreads();
#pragma unroll
    for (int i = 0; i < 4; ++i) {
        int idx = i * 256 + tid;
        int row = idx >> 4;             // 16 chunks of 8 halfs per 128-col row
        int c8 = (idx & 15) * 8;
        if (row0 + row < N_NODES) {
            f16x8 xv = *(const f16x8*)&hs[row * 136 + c8];
            *(f16x8*)(Hh + (size_t)(row0 + row) * 256 + c0 + c8) = xv;
        }
    }
}

// ---------------- GEMM K=64(41 padded) via MFMA fp16, B-in-LDS, 64x128 blocks ----------------

__global__ __launch_bounds__(256) void gemm41h(const _Float16* __restrict__ Xh,
                                               const _Float16* __restrict__ W1t,
                                               const float* __restrict__ a_src,
                                               const float* __restrict__ a_dst,
                                               _Float16* __restrict__ Hh,
                                               float* __restrict__ ssrc,
                                               float* __restrict__ sdst) {
    __shared__ _Float16 bs[128 * 72];   // 18.4 KB; reused as hs[64*136] (17.4 KB) after compute
    int row0 = (blockIdx.x >> 1) * 64;
    int half = blockIdx.x & 1;
    int c0 = half * 128;
    int tid = threadIdx.x;
    int lane = tid & 63;
    int v = tid >> 6;
    int r16 = lane & 15;
    int kseg = lane >> 4;

    // stage B: 128 cols x 64 K = 1024 chunks of 8 halfs, 4/thread
#pragma unroll
    for (int i = 0; i < 4; ++i) {
        int chunk = i * 256 + tid;
        int c = chunk >> 3;
        int k = (chunk & 7) * 8;
        f16x8 xv = *(const f16x8*)(W1t + (size_t)(c0 + c) * 64 + k);
        *(f16x8*)(&bs[c * 72 + k]) = xv;
    }

    int arow = row0 + v * 16 + r16;
    const _Float16* XA = Xh + (size_t)arow * 64 + kseg * 8;
    f16x8 af[2];
    af[0] = *(const f16x8*)(XA);
    af[1] = *(const f16x8*)(XA + 32);

    __syncthreads();

    f32x4v acc[8];
#pragma unroll
    for (int tn = 0; tn < 8; ++tn) acc[tn] = (f32x4v){0.f, 0.f, 0.f, 0.f};

#pragma unroll
    for (int tn = 0; tn < 8; ++tn) {
        f16x8 bf0 = *(const f16x8*)(&bs[(tn * 16 + r16) * 72 + kseg * 8]);
        f16x8 bf1 = *(const f16x8*)(&bs[(tn * 16 + r16) * 72 + kseg * 8 + 32]);
        acc[tn] = __builtin_amdgcn_mfma_f32_16x16x32_f16(af[0], bf0, acc[tn], 0, 0, 0);
        acc[tn] = __builtin_amdgcn_mfma_f32_16x16x32_f16(af[1], bf1, acc[tn], 0, 0, 0);
    }

#pragma unroll
    for (int hh = 0; hh < 4; ++hh) {
        float as0 = a_src[c0 + hh * 32 + r16], as1 = a_src[c0 + hh * 32 + 16 + r16];
        float ad0 = a_dst[c0 + hh * 32 + r16], ad1 = a_dst[c0 + hh * 32 + 16 + r16];
#pragma unroll
        for (int r = 0; r < 4; ++r) {
            float p = acc[2 * hh][r] * as0 + acc[2 * hh + 1][r] * as1;
            float q = acc[2 * hh][r] * ad0 + acc[2 * hh + 1][r] * ad1;
            p += __shfl_xor(p, 1); q += __shfl_xor(q, 1);
            p += __shfl_xor(p, 2); q += __shfl_xor(q, 2);
            p += __shfl_xor(p, 4); q += __shfl_xor(q, 4);
            p += __shfl_xor(p, 8); q += __shfl_xor(q, 8);
            int row = row0 + v * 16 + kseg * 4 + r;
            if (r16 == 0 && row < N_NODES) {
                ssrc[row * NH + half * 4 + hh] = p;
                sdst[row * NH + half * 4 + hh] = q;
            }
        }
    }

    __syncthreads();
    _Float16* hs = bs;
#pragma unroll
    for (int tn = 0; tn < 8; ++tn)
#pragma unroll
        for (int r = 0; r < 4; ++r)
            hs[(v * 16 + kseg * 4 + r) * 136 + tn * 16 + r16] = (_Float16)acc[tn][r];
    __syncthreads();
#pragma unroll
    for (int i = 0; i < 4; ++i) {
        int idx = i * 256 + tid;
        int row = idx >> 4;
        int c8 = (idx & 15) * 8;
        if (row0 + row < N_NODES) {
            f16x8 xv = *(const f16x8*)&hs[row * 136 + c8];
            *(f16x8*)(Hh + (size_t)(row0 + row) * 256 + c0 + c8) = xv;
        }
    }
}

// ---------------- fused GAT aggregation + bias + BN(eval) + ELU ----------------
// Single pass (softmax shift-invariance; scores O(1) -> exp safe in fp32).

__global__ __launch_bounds__(256) void gat_agg(const int* __restrict__ row_ptr,
                                               const int* __restrict__ colidx,
                                               const float* __restrict__ ssrc,
                                               const float* __restrict__ sdst,
                                               const _Float16* __restrict__ h,
                                               const float* __restrict__ bias,
                                               const float* __restrict__ gamma,
                                               const float* __restrict__ beta,
                                               _Float16* __restrict__ outh) {
    int wave = (blockIdx.x * blockDim.x + threadIdx.x) >> 6;
    int lane = threadIdx.x & 63;
    if (wave >= N_NODES) return;
    int n = wave;
    int beg = row_ptr[n], end = row_ptr[n + 1];
    int deg = end - beg;

    int hd = lane >> 3;
    float sd = sdst[n * NH + hd];
    int c = lane * 4;
    float acc0 = 0.f, acc1 = 0.f, acc2 = 0.f, acc3 = 0.f, denom = 0.f;

    int i = 0;
    for (; i + 8 <= deg; i += 8) {
        int sidx[8];
#pragma unroll
        for (int j = 0; j < 8; ++j) sidx[j] = colidx[beg + i + j];
        float wv[8];
#pragma unroll
        for (int j = 0; j < 8; ++j) {
            float v = ssrc[sidx[j] * NH + hd] + sd;
            v = (v >= 0.f) ? v : 0.2f * v;
            wv[j] = __expf(v);
        }
        f16x4 hv[8];
#pragma unroll
        for (int j = 0; j < 8; ++j) hv[j] = *reinterpret_cast<const f16x4*>(h + (size_t)sidx[j] * HC + c);
#pragma unroll
        for (int j = 0; j < 8; ++j) {
            denom += wv[j];
            acc0 += wv[j] * (float)hv[j][0];
            acc1 += wv[j] * (float)hv[j][1];
            acc2 += wv[j] * (float)hv[j][2];
            acc3 += wv[j] * (float)hv[j][3];
        }
    }
    for (; i < deg; ++i) {
        int s = colidx[beg + i];
        float v = ssrc[s * NH + hd] + sd;
        v = (v >= 0.f) ? v : 0.2f * v;
        float wgt = __expf(v);
        denom += wgt;
        const f16x4 hv = *reinterpret_cast<const f16x4*>(h + (size_t)s * HC + c);
        acc0 += wgt * (float)hv[0]; acc1 += wgt * (float)hv[1];
        acc2 += wgt * (float)hv[2]; acc3 += wgt * (float)hv[3];
    }
    float inv = 1.0f / denom;
    const float bninv = 0.99999500003749981f;  // 1/sqrt(1+1e-5)
    float vals[4] = {acc0, acc1, acc2, acc3};
    f16x4 o;
#pragma unroll
    for (int j = 0; j < 4; ++j) {
        float v = vals[j] * inv + bias[c + j];
        v = v * (gamma[c + j] * bninv) + beta[c + j];
        v = (v > 0.f) ? v : (__expf(v) - 1.0f);
        o[j] = (_Float16)v;
    }
    *(f16x4*)(outh + (size_t)n * HC + c) = o;
}

// ---------------- pooling ----------------

__global__ __launch_bounds__(256) void pool_partial(const _Float16* __restrict__ h,
                                                    const int* __restrict__ gstart,
                                                    const int* __restrict__ gend,
                                                    float* __restrict__ psum,
                                                    float* __restrict__ pmax) {
    int g = blockIdx.x >> 4;
    int c = blockIdx.x & (PCHUNK - 1);
    int t = threadIdx.x;
    int s = gstart[g], e = gend[g];
    int len = e - s;
    int n0 = s + (int)(((long long)len * c) / PCHUNK);
    int n1 = s + (int)(((long long)len * (c + 1)) / PCHUNK);
    float sum = 0.f, mx = -3.0e38f;
    for (int n = n0; n < n1; ++n) {
        float v = (float)h[(size_t)n * HC + t];
        sum += v;
        mx = fmaxf(mx, v);
    }
    psum[(size_t)(g * PCHUNK + c) * HC + t] = sum;
    pmax[(size_t)(g * PCHUNK + c) * HC + t] = mx;
}

// ---------------- MLP head (fused pool-finalize + 3 FC layers) ----------------

__global__ __launch_bounds__(256) void mlp(const float* __restrict__ psum,
                                           const float* __restrict__ pmax,
                                           const int* __restrict__ gstart,
                                           const int* __restrict__ gend,
                                           const float* __restrict__ gsz,
                                           const float* __restrict__ fc1wT, const float* __restrict__ fc1b,
                                           const float* __restrict__ gf1, const float* __restrict__ bf1,
                                           const float* __restrict__ fc2w, const float* __restrict__ fc2b,
                                           const float* __restrict__ gf2, const float* __restrict__ bf2,
                                           const float* __restrict__ fc3w, const float* __restrict__ fc3b,
                                           float* __restrict__ out) {
    __shared__ __align__(16) float pr[514];
    __shared__ float z1[64];
    __shared__ float zz2[8][32];
    __shared__ float z2[32];
    int g = blockIdx.x;
    int t = threadIdx.x;
    const float bninv = 0.99999500003749981f;

    {
        float s = 0.f, m = -3.0e38f;
#pragma unroll
        for (int c = 0; c < PCHUNK; ++c) {
            s += psum[(size_t)(g * PCHUNK + c) * HC + t];
            m = fmaxf(m, pmax[(size_t)(g * PCHUNK + c) * HC + t]);
        }
        float cnt = (float)(gend[g] - gstart[g]);
        pr[t] = s / fmaxf(cnt, 1.f);
        pr[256 + t] = m;
        if (t < 2) pr[512 + t] = gsz[g * 2 + t];
    }
    __syncthreads();

    {
        int wv = t >> 6, lane = t & 63;
        float4 pa = *reinterpret_cast<const float4*>(&pr[lane * 8]);
        float4 pb = *reinterpret_cast<const float4*>(&pr[lane * 8 + 4]);
#pragma unroll 4
        for (int i = 0; i < 16; ++i) {
            int u = wv * 16 + i;
            const float* wrow = fc1wT + u * 520;
            float4 wa = *reinterpret_cast<const float4*>(wrow + lane * 8);
            float4 wb = *reinterpret_cast<const float4*>(wrow + lane * 8 + 4);
            float a = pa.x * wa.x + pa.y * wa.y + pa.z * wa.z + pa.w * wa.w
                    + pb.x * wb.x + pb.y * wb.y + pb.z * wb.z + pb.w * wb.w;
            if (lane == 0) a += pr[512] * wrow[512] + pr[513] * wrow[513];
            a += __shfl_xor(a, 1); a += __shfl_xor(a, 2); a += __shfl_xor(a, 4);
            a += __shfl_xor(a, 8); a += __shfl_xor(a, 16); a += __shfl_xor(a, 32);
            if (lane == 0) {
                a += fc1b[u];
                a = a * (gf1[u] * bninv) + bf1[u];
                z1[u] = fmaxf(a, 0.f);
            }
        }
    }
    __syncthreads();

    {
        int u = t & 31, sp = t >> 5;
        float b = 0.f;
#pragma unroll
        for (int k = sp * 8; k < sp * 8 + 8; ++k) b += z1[k] * fc2w[k * 32 + u];
        zz2[sp][u] = b;
    }
    __syncthreads();
    if (t < 32) {
        float b = 0.f;
#pragma unroll
        for (int sp = 0; sp < 8; ++sp) b += zz2[sp][t];
        b += fc2b[t];
        b = b * (gf2[t] * bninv) + bf2[t];
        z2[t] = fmaxf(b, 0.f);
    }
    __syncthreads();

    if (t < 2) {
        float c = 0.f;
#pragma unroll
        for (int k = 0; k < 32; ++k) c += z2[k] * fc3w[k * 2 + t];
        out[g * 2 + t] = c + fc3b[t];
    }
}

// ---------------- launch ----------------

extern "C" void kernel_launch(void* const* d_in, const int* in_sizes, int n_in,
                              void* d_out, int out_size, void* d_ws, size_t ws_size,
                              hipStream_t stream) {
    const float* x    = (const float*)d_in[0];
    const int*   ei   = (const int*)d_in[1];
    const int*   batch= (const int*)d_in[2];
    const float* gsz  = (const float*)d_in[3];
    const float* W1   = (const float*)d_in[4];
    const float* as1  = (const float*)d_in[5];
    const float* ad1  = (const float*)d_in[6];
    const float* b1   = (const float*)d_in[7];
    const float* g1   = (const float*)d_in[8];
    const float* be1  = (const float*)d_in[9];
    const float* W2   = (const float*)d_in[10];
    const float* as2  = (const float*)d_in[11];
    const float* ad2  = (const float*)d_in[12];
    const float* b2   = (const float*)d_in[13];
    const float* g2   = (const float*)d_in[14];
    const float* be2  = (const float*)d_in[15];
    const float* fc1w = (const float*)d_in[16];
    const float* fc1b = (const float*)d_in[17];
    const float* gf1  = (const float*)d_in[18];
    const float* bf1  = (const float*)d_in[19];
    const float* fc2w = (const float*)d_in[20];
    const float* fc2b = (const float*)d_in[21];
    const float* gf2  = (const float*)d_in[22];
    const float* bf2  = (const float*)d_in[23];
    const float* fc3w = (const float*)d_in[24];
    const float* fc3b = (const float*)d_in[25];
    float* out = (float*)d_out;

    char* w = (char*)d_ws;
    _Float16* h_half   = (_Float16*)w; w += (size_t)N_NODES * HC * 2;   // 10.24 MB
    _Float16* act_half = (_Float16*)w; w += (size_t)N_NODES * HC * 2;   // 10.24 MB
    _Float16* act2_half= (_Float16*)w; w += (size_t)N_NODES * HC * 2;   // 10.24 MB
    _Float16* Wt       = (_Float16*)w; w += (size_t)HC * HC * 2;        // 128 KB
    _Float16* W1t      = (_Float16*)w; w += (size_t)HC * 64 * 2;        // 32 KB
    _Float16* xpad     = (_Float16*)w; w += (size_t)NPAD * 64 * 2;      // 2.56 MB
    float* fc1wT       = (float*)w;    w += (size_t)64 * 520 * 4;       // 133 KB
    float* ssrc        = (float*)w;    w += (size_t)N_NODES * NH * 4;
    float* sdst        = (float*)w;    w += (size_t)N_NODES * NH * 4;
    int* row_ptr  = (int*)w;   w += (size_t)(N_NODES + 1) * 4;
    int* cursor   = (int*)w;   w += (size_t)N_NODES * 4;
    // cnt, gstart, gend contiguous -> single memset
    int* cnt      = (int*)w;   w += (size_t)N_NODES * 4;
    int* gstart   = (int*)w;   w += 64 * 4;
    int* gend     = (int*)w;   w += 64 * 4;
    int* colidx   = (int*)w;   w += (size_t)(E_EDGES + N_NODES) * 4;
    int* partial  = (int*)w;   w += 64 * 4;

    // pool partials alias h_half (dead after gat_agg#2)
    float* psum = (float*)h_half;
    float* pmax = psum + (size_t)NG * PCHUNK * HC;

    hipMemsetAsync(cnt, 0, (size_t)(N_NODES + 128) * 4, stream);  // cnt + gstart + gend

    prep<<<914, 256, 0, stream>>>(W2, Wt, fc1w, fc1wT, batch, gstart, gend, W1, W1t, x, xpad);
    hist<<<1250, 256, 0, stream>>>(ei, cnt);
    scanA<<<40, 512, 0, stream>>>(cnt, partial);
    scanC<<<40, 512, 0, stream>>>(cnt, partial, row_ptr, cursor, colidx);
    fill_csr<<<1250, 256, 0, stream>>>(ei, cursor, colidx);

    gemm41h<<<626, 256, 0, stream>>>(xpad, W1t, as1, ad1, h_half, ssrc, sdst);
    gat_agg<<<5000, 256, 0, stream>>>(row_ptr, colidx, ssrc, sdst, h_half, b1, g1, be1, act_half);

    gemm256h<<<626, 256, 0, stream>>>(act_half, Wt, as2, ad2, h_half, ssrc, sdst);
    gat_agg<<<5000, 256, 0, stream>>>(row_ptr, colidx, ssrc, sdst, h_half, b2, g2, be2, act2_half);

    pool_partial<<<NG * PCHUNK, 256, 0, stream>>>(act2_half, gstart, gend, psum, pmax);
    mlp<<<NG, 256, 0, stream>>>(psum, pmax, gstart, gend, gsz,
                                fc1wT, fc1b, gf1, bf1, fc2w, fc2b, gf2, bf2, fc3w, fc3b, out);
}

// Round 15
// 160.622 us; speedup vs baseline: 1.0398x; 1.0398x over previous
//
#include <hip/hip_runtime.h>
#include <hip/hip_bf16.h>

#define N_NODES 20000
#define E_EDGES 320000
#define NH 8
#define NC 32
#define HC 256
#define FIN 41
#define NG 64
#define PCHUNK 16
#define NPAD 20032

typedef _Float16 f16x4 __attribute__((ext_vector_type(4)));
typedef _Float16 f16x8 __attribute__((ext_vector_type(8)));
typedef float f32x4v __attribute__((ext_vector_type(4)));

// ---------------- CSR build ----------------
// cnt[] holds EDGE counts only (zeroed by memset); row size = cnt[n] + 1 (self loop).

__global__ __launch_bounds__(512) void scanA(const int* __restrict__ cnt, int* partial) {
    __shared__ int red[512];
    int n = blockIdx.x * 512 + threadIdx.x;
    int v = (n < N_NODES) ? cnt[n] + 1 : 0;
    red[threadIdx.x] = v; __syncthreads();
    for (int off = 256; off > 0; off >>= 1) {
        if (threadIdx.x < off) red[threadIdx.x] += red[threadIdx.x + off];
        __syncthreads();
    }
    if (threadIdx.x == 0) partial[blockIdx.x] = red[0];
}

// scanC with inlined cross-block prefix (first wave shfl-scans the 40 partials)
__global__ __launch_bounds__(512) void scanC(const int* __restrict__ cnt, const int* __restrict__ partial,
                                             int* row_ptr, int* cursor, int* colidx) {
    __shared__ int buf[512];
    __shared__ int pbase;
    int t = threadIdx.x;
    if (t < 64) {
        int v = (t < 40) ? partial[t] : 0;
        int own = v;
        for (int off = 1; off < 64; off <<= 1) {
            int y = __shfl_up(v, off);
            if (t >= off) v += y;
        }
        if (t == (int)blockIdx.x) pbase = v - own;  // exclusive prefix at blockIdx.x
    }
    int n = blockIdx.x * 512 + t;
    int v = (n < N_NODES) ? cnt[n] + 1 : 0;
    int x = v;
    buf[t] = x; __syncthreads();
    for (int off = 1; off < 512; off <<= 1) {
        int y = (t >= off) ? buf[t - off] : 0;
        __syncthreads();
        x += y; buf[t] = x; __syncthreads();
    }
    int excl = pbase + x - v;
    if (n < N_NODES) {
        row_ptr[n] = excl;
        cursor[n] = excl + 1;     // self loop occupies slot 0
        colidx[excl] = n;         // self loop
    }
    if (n == 0) row_ptr[N_NODES] = E_EDGES + N_NODES;
}

__global__ __launch_bounds__(256) void fill_csr(const int* __restrict__ ei, int* cursor, int* colidx) {
    int e = blockIdx.x * 256 + threadIdx.x;
    if (e >= E_EDGES) return;
    int d = ei[E_EDGES + e];
    int s = ei[e];
    int pos = atomicAdd(&cursor[d], 1);
    colidx[pos] = s;
}

// ---------------- prep (+ fused hist) ----------------
// blocks 0..15:     W2 -> fp16 col-major Wt[256][256]
// blocks 16..144:   fc1w -> fc1wT[64][520]
// blocks 145..223:  graph_ranges
// blocks 224..287:  W1 [41][256] -> fp16 col-major W1t[256][64] (zero-padded K)
// blocks 288..913:  x [20000][41] -> fp16 xpad[20032][64] (zero-padded)
// blocks 914..2163: hist (dst-degree histogram; cnt pre-zeroed by memset)

__global__ __launch_bounds__(256) void prep(const float* __restrict__ W, _Float16* __restrict__ Wt,
                                            const float* __restrict__ fc1w, float* __restrict__ fc1wT,
                                            const int* __restrict__ batch, int* gstart, int* gend,
                                            const float* __restrict__ W1, _Float16* __restrict__ W1t,
                                            const float* __restrict__ x, _Float16* __restrict__ xpad,
                                            const int* __restrict__ ei, int* cnt) {
    __shared__ float tile[64][65];
    int b = blockIdx.x;
    int t = threadIdx.x;
    if (b < 16) {
        int tr = (b >> 2) * 64;
        int tc = (b & 3) * 64;
        int rr = t >> 6, cc = t & 63;
#pragma unroll
        for (int j = 0; j < 16; ++j) {
            int row = j * 4 + rr;
            tile[row][cc] = W[(size_t)(tr + row) * 256 + tc + cc];
        }
        __syncthreads();
#pragma unroll
        for (int j = 0; j < 16; ++j) {
            int row = j * 4 + rr;
            Wt[(size_t)(tc + row) * 256 + tr + cc] = (_Float16)tile[cc][row];
        }
    } else if (b < 145) {
        int id = (b - 16) * 256 + t;
        if (id < 64 * 514) {
            int u = id / 514, kk = id - u * 514;
            fc1wT[u * 520 + kk] = fc1w[kk * 64 + u];
        }
    } else if (b < 224) {
        int n = (b - 145) * 256 + t;
        if (n < N_NODES) {
            int bb = batch[n];
            if (n == 0) gstart[bb] = 0;
            else {
                int pb = batch[n - 1];
                if (pb != bb) { gstart[bb] = n; gend[pb] = n; }
            }
            if (n == N_NODES - 1) gend[bb] = N_NODES;
        }
    } else if (b < 288) {
        int id = (b - 224) * 256 + t;       // 16384 = 256 cols x 64 K
        int n = id >> 6, k = id & 63;
        W1t[id] = (k < FIN) ? (_Float16)W1[k * 256 + n] : (_Float16)0.f;
    } else if (b < 914) {
        int row = (b - 288) * 32 + (t >> 3);
        int c8 = (t & 7) * 8;
        f16x8 v;
#pragma unroll
        for (int j = 0; j < 8; ++j) {
            int c = c8 + j;
            float f = (row < N_NODES && c < FIN) ? x[(size_t)row * FIN + c] : 0.f;
            v[j] = (_Float16)f;
        }
        if (row < NPAD) *(f16x8*)(xpad + (size_t)row * 64 + c8) = v;
    } else {
        int e = (b - 914) * 256 + t;
        if (e < E_EDGES) atomicAdd(&cnt[ei[E_EDGES + e]], 1);
    }
}

// ---------------- GEMM K=256 via MFMA fp16 (16x16x32), B-in-LDS, 64x128 blocks ----------------

__global__ __launch_bounds__(256) void gemm256h(const _Float16* __restrict__ Xh,
                                                const _Float16* __restrict__ Wt,
                                                const float* __restrict__ a_src,
                                                const float* __restrict__ a_dst,
                                                _Float16* __restrict__ Hh,
                                                float* __restrict__ ssrc,
                                                float* __restrict__ sdst) {
    __shared__ _Float16 bs[128 * 272];          // 69.6 KB; reused as hs[64*136] after compute
    int row0 = (blockIdx.x >> 1) * 64;
    int half = blockIdx.x & 1;
    int c0 = half * 128;
    int tid = threadIdx.x;
    int lane = tid & 63;
    int v = tid >> 6;
    int r16 = lane & 15;
    int kseg = lane >> 4;

#pragma unroll
    for (int i = 0; i < 16; ++i) {
        int chunk = i * 256 + tid;
        int c = chunk >> 5;
        int k = (chunk & 31) * 8;
        f16x8 xv = *(const f16x8*)(Wt + (size_t)(c0 + c) * 256 + k);
        *(f16x8*)(&bs[c * 272 + k]) = xv;
    }

    int arow = row0 + v * 16 + r16;
    const _Float16* XA = Xh + (size_t)arow * 256 + kseg * 8;
    f16x8 af[8];
#pragma unroll
    for (int s = 0; s < 8; ++s) af[s] = *(const f16x8*)(XA + s * 32);

    __syncthreads();

    f32x4v acc[8];
#pragma unroll
    for (int tn = 0; tn < 8; ++tn) acc[tn] = (f32x4v){0.f, 0.f, 0.f, 0.f};

#pragma unroll
    for (int tn = 0; tn < 8; ++tn) {
        f16x8 bf[8];
#pragma unroll
        for (int s = 0; s < 8; ++s)
            bf[s] = *(const f16x8*)(&bs[(tn * 16 + r16) * 272 + kseg * 8 + s * 32]);
#pragma unroll
        for (int s = 0; s < 8; ++s)
            acc[tn] = __builtin_amdgcn_mfma_f32_16x16x32_f16(af[s], bf[s], acc[tn], 0, 0, 0);
    }

#pragma unroll
    for (int hh = 0; hh < 4; ++hh) {
        float as0 = a_src[c0 + hh * 32 + r16], as1 = a_src[c0 + hh * 32 + 16 + r16];
        float ad0 = a_dst[c0 + hh * 32 + r16], ad1 = a_dst[c0 + hh * 32 + 16 + r16];
#pragma unroll
        for (int r = 0; r < 4; ++r) {
            float p = acc[2 * hh][r] * as0 + acc[2 * hh + 1][r] * as1;
            float q = acc[2 * hh][r] * ad0 + acc[2 * hh + 1][r] * ad1;
            p += __shfl_xor(p, 1); q += __shfl_xor(q, 1);
            p += __shfl_xor(p, 2); q += __shfl_xor(q, 2);
            p += __shfl_xor(p, 4); q += __shfl_xor(q, 4);
            p += __shfl_xor(p, 8); q += __shfl_xor(q, 8);
            int row = row0 + v * 16 + kseg * 4 + r;
            if (r16 == 0 && row < N_NODES) {
                ssrc[row * NH + half * 4 + hh] = p;
                sdst[row * NH + half * 4 + hh] = q;
            }
        }
    }

    __syncthreads();
    _Float16* hs = bs;
#pragma unroll
    for (int tn = 0; tn < 8; ++tn)
#pragma unroll
        for (int r = 0; r < 4; ++r)
            hs[(v * 16 + kseg * 4 + r) * 136 + tn * 16 + r16] = (_Float16)acc[tn][r];
    __syncthreads();
#pragma unroll
    for (int i = 0; i < 4; ++i) {
        int idx = i * 256 + tid;
        int row = idx >> 4;
        int c8 = (idx & 15) * 8;
        if (row0 + row < N_NODES) {
            f16x8 xv = *(const f16x8*)&hs[row * 136 + c8];
            *(f16x8*)(Hh + (size_t)(row0 + row) * 256 + c0 + c8) = xv;
        }
    }
}

// ---------------- GEMM K=64(41 padded) via MFMA fp16, B-in-LDS, 64x128 blocks ----------------

__global__ __launch_bounds__(256) void gemm41h(const _Float16* __restrict__ Xh,
                                               const _Float16* __restrict__ W1t,
                                               const float* __restrict__ a_src,
                                               const float* __restrict__ a_dst,
                                               _Float16* __restrict__ Hh,
                                               float* __restrict__ ssrc,
                                               float* __restrict__ sdst) {
    __shared__ _Float16 bs[128 * 72];
    __shared__ _Float16 hs[64 * 136];
    int row0 = (blockIdx.x >> 1) * 64;
    int half = blockIdx.x & 1;
    int c0 = half * 128;
    int tid = threadIdx.x;
    int lane = tid & 63;
    int v = tid >> 6;
    int r16 = lane & 15;
    int kseg = lane >> 4;

#pragma unroll
    for (int i = 0; i < 4; ++i) {
        int chunk = i * 256 + tid;
        int c = chunk >> 3;
        int k = (chunk & 7) * 8;
        f16x8 xv = *(const f16x8*)(W1t + (size_t)(c0 + c) * 64 + k);
        *(f16x8*)(&bs[c * 72 + k]) = xv;
    }

    int arow = row0 + v * 16 + r16;
    const _Float16* XA = Xh + (size_t)arow * 64 + kseg * 8;
    f16x8 af[2];
    af[0] = *(const f16x8*)(XA);
    af[1] = *(const f16x8*)(XA + 32);

    __syncthreads();

    f32x4v acc[8];
#pragma unroll
    for (int tn = 0; tn < 8; ++tn) acc[tn] = (f32x4v){0.f, 0.f, 0.f, 0.f};

#pragma unroll
    for (int tn = 0; tn < 8; ++tn) {
        f16x8 bf0 = *(const f16x8*)(&bs[(tn * 16 + r16) * 72 + kseg * 8]);
        f16x8 bf1 = *(const f16x8*)(&bs[(tn * 16 + r16) * 72 + kseg * 8 + 32]);
        acc[tn] = __builtin_amdgcn_mfma_f32_16x16x32_f16(af[0], bf0, acc[tn], 0, 0, 0);
        acc[tn] = __builtin_amdgcn_mfma_f32_16x16x32_f16(af[1], bf1, acc[tn], 0, 0, 0);
    }

#pragma unroll
    for (int hh = 0; hh < 4; ++hh) {
        float as0 = a_src[c0 + hh * 32 + r16], as1 = a_src[c0 + hh * 32 + 16 + r16];
        float ad0 = a_dst[c0 + hh * 32 + r16], ad1 = a_dst[c0 + hh * 32 + 16 + r16];
#pragma unroll
        for (int r = 0; r < 4; ++r) {
            float p = acc[2 * hh][r] * as0 + acc[2 * hh + 1][r] * as1;
            float q = acc[2 * hh][r] * ad0 + acc[2 * hh + 1][r] * ad1;
            p += __shfl_xor(p, 1); q += __shfl_xor(q, 1);
            p += __shfl_xor(p, 2); q += __shfl_xor(q, 2);
            p += __shfl_xor(p, 4); q += __shfl_xor(q, 4);
            p += __shfl_xor(p, 8); q += __shfl_xor(q, 8);
            int row = row0 + v * 16 + kseg * 4 + r;
            if (r16 == 0 && row < N_NODES) {
                ssrc[row * NH + half * 4 + hh] = p;
                sdst[row * NH + half * 4 + hh] = q;
            }
        }
    }

    __syncthreads();
#pragma unroll
    for (int tn = 0; tn < 8; ++tn)
#pragma unroll
        for (int r = 0; r < 4; ++r)
            hs[(v * 16 + kseg * 4 + r) * 136 + tn * 16 + r16] = (_Float16)acc[tn][r];
    __syncthreads();
#pragma unroll
    for (int i = 0; i < 4; ++i) {
        int idx = i * 256 + tid;
        int row = idx >> 4;
        int c8 = (idx & 15) * 8;
        if (row0 + row < N_NODES) {
            f16x8 xv = *(const f16x8*)&hs[row * 136 + c8];
            *(f16x8*)(Hh + (size_t)(row0 + row) * 256 + c0 + c8) = xv;
        }
    }
}

// ---------------- fused GAT aggregation + bias + BN(eval) + ELU ----------------
// Single pass (softmax shift-invariance; scores O(1) -> exp safe in fp32).

__global__ __launch_bounds__(256) void gat_agg(const int* __restrict__ row_ptr,
                                               const int* __restrict__ colidx,
                                               const float* __restrict__ ssrc,
                                               const float* __restrict__ sdst,
                                               const _Float16* __restrict__ h,
                                               const float* __restrict__ bias,
                                               const float* __restrict__ gamma,
                                               const float* __restrict__ beta,
                                               _Float16* __restrict__ outh) {
    int wave = (blockIdx.x * blockDim.x + threadIdx.x) >> 6;
    int lane = threadIdx.x & 63;
    if (wave >= N_NODES) return;
    int n = wave;
    int beg = row_ptr[n], end = row_ptr[n + 1];
    int deg = end - beg;

    int hd = lane >> 3;
    float sd = sdst[n * NH + hd];
    int c = lane * 4;
    float acc0 = 0.f, acc1 = 0.f, acc2 = 0.f, acc3 = 0.f, denom = 0.f;

    int i = 0;
    for (; i + 8 <= deg; i += 8) {
        int sidx[8];
#pragma unroll
        for (int j = 0; j < 8; ++j) sidx[j] = colidx[beg + i + j];
        float wv[8];
#pragma unroll
        for (int j = 0; j < 8; ++j) {
            float v = ssrc[sidx[j] * NH + hd] + sd;
            v = (v >= 0.f) ? v : 0.2f * v;
            wv[j] = __expf(v);
        }
        f16x4 hv[8];
#pragma unroll
        for (int j = 0; j < 8; ++j) hv[j] = *reinterpret_cast<const f16x4*>(h + (size_t)sidx[j] * HC + c);
#pragma unroll
        for (int j = 0; j < 8; ++j) {
            denom += wv[j];
            acc0 += wv[j] * (float)hv[j][0];
            acc1 += wv[j] * (float)hv[j][1];
            acc2 += wv[j] * (float)hv[j][2];
            acc3 += wv[j] * (float)hv[j][3];
        }
    }
    for (; i < deg; ++i) {
        int s = colidx[beg + i];
        float v = ssrc[s * NH + hd] + sd;
        v = (v >= 0.f) ? v : 0.2f * v;
        float wgt = __expf(v);
        denom += wgt;
        const f16x4 hv = *reinterpret_cast<const f16x4*>(h + (size_t)s * HC + c);
        acc0 += wgt * (float)hv[0]; acc1 += wgt * (float)hv[1];
        acc2 += wgt * (float)hv[2]; acc3 += wgt * (float)hv[3];
    }
    float inv = 1.0f / denom;
    const float bninv = 0.99999500003749981f;  // 1/sqrt(1+1e-5)
    float vals[4] = {acc0, acc1, acc2, acc3};
    f16x4 o;
#pragma unroll
    for (int j = 0; j < 4; ++j) {
        float v = vals[j] * inv + bias[c + j];
        v = v * (gamma[c + j] * bninv) + beta[c + j];
        v = (v > 0.f) ? v : (__expf(v) - 1.0f);
        o[j] = (_Float16)v;
    }
    *(f16x4*)(outh + (size_t)n * HC + c) = o;
}

// ---------------- pooling (vectorized: 4 waves x f16x4/lane, LDS 4-way reduce) ----------------

__global__ __launch_bounds__(256) void pool_partial(const _Float16* __restrict__ h,
                                                    const int* __restrict__ gstart,
                                                    const int* __restrict__ gend,
                                                    float* __restrict__ psum,
                                                    float* __restrict__ pmax) {
    __shared__ float ssm[4][256];
    __shared__ float smx[4][256];
    int g = blockIdx.x >> 4;
    int c = blockIdx.x & (PCHUNK - 1);
    int t = threadIdx.x;
    int wv = t >> 6;
    int lane = t & 63;
    int c4 = lane * 4;
    int s = gstart[g], e = gend[g];
    int len = e - s;
    int n0 = s + (int)(((long long)len * c) / PCHUNK);
    int n1 = s + (int)(((long long)len * (c + 1)) / PCHUNK);
    float s0 = 0.f, s1 = 0.f, s2 = 0.f, s3 = 0.f;
    float m0 = -3.0e38f, m1 = -3.0e38f, m2 = -3.0e38f, m3 = -3.0e38f;
    for (int n = n0 + wv; n < n1; n += 4) {
        f16x4 v = *(const f16x4*)(h + (size_t)n * HC + c4);
        float f0 = (float)v[0], f1 = (float)v[1], f2 = (float)v[2], f3 = (float)v[3];
        s0 += f0; s1 += f1; s2 += f2; s3 += f3;
        m0 = fmaxf(m0, f0); m1 = fmaxf(m1, f1); m2 = fmaxf(m2, f2); m3 = fmaxf(m3, f3);
    }
    ssm[wv][c4] = s0; ssm[wv][c4 + 1] = s1; ssm[wv][c4 + 2] = s2; ssm[wv][c4 + 3] = s3;
    smx[wv][c4] = m0; smx[wv][c4 + 1] = m1; smx[wv][c4 + 2] = m2; smx[wv][c4 + 3] = m3;
    __syncthreads();
    float fs = ssm[0][t] + ssm[1][t] + ssm[2][t] + ssm[3][t];
    float fm = fmaxf(fmaxf(smx[0][t], smx[1][t]), fmaxf(smx[2][t], smx[3][t]));
    size_t base = (size_t)(g * PCHUNK + c) * HC + t;
    psum[base] = fs;
    pmax[base] = fm;
}

// ---------------- MLP head (fused pool-finalize + 3 FC layers) ----------------

__global__ __launch_bounds__(256) void mlp(const float* __restrict__ psum,
                                           const float* __restrict__ pmax,
                                           const int* __restrict__ gstart,
                                           const int* __restrict__ gend,
                                           const float* __restrict__ gsz,
                                           const float* __restrict__ fc1wT, const float* __restrict__ fc1b,
                                           const float* __restrict__ gf1, const float* __restrict__ bf1,
                                           const float* __restrict__ fc2w, const float* __restrict__ fc2b,
                                           const float* __restrict__ gf2, const float* __restrict__ bf2,
                                           const float* __restrict__ fc3w, const float* __restrict__ fc3b,
                                           float* __restrict__ out) {
    __shared__ __align__(16) float pr[514];
    __shared__ float z1[64];
    __shared__ float zz2[8][32];
    __shared__ float z2[32];
    int g = blockIdx.x;
    int t = threadIdx.x;
    const float bninv = 0.99999500003749981f;

    {
        float s = 0.f, m = -3.0e38f;
#pragma unroll
        for (int c = 0; c < PCHUNK; ++c) {
            s += psum[(size_t)(g * PCHUNK + c) * HC + t];
            m = fmaxf(m, pmax[(size_t)(g * PCHUNK + c) * HC + t]);
        }
        float cnt = (float)(gend[g] - gstart[g]);
        pr[t] = s / fmaxf(cnt, 1.f);
        pr[256 + t] = m;
        if (t < 2) pr[512 + t] = gsz[g * 2 + t];
    }
    __syncthreads();

    {
        int wv = t >> 6, lane = t & 63;
        float4 pa = *reinterpret_cast<const float4*>(&pr[lane * 8]);
        float4 pb = *reinterpret_cast<const float4*>(&pr[lane * 8 + 4]);
#pragma unroll 4
        for (int i = 0; i < 16; ++i) {
            int u = wv * 16 + i;
            const float* wrow = fc1wT + u * 520;
            float4 wa = *reinterpret_cast<const float4*>(wrow + lane * 8);
            float4 wb = *reinterpret_cast<const float4*>(wrow + lane * 8 + 4);
            float a = pa.x * wa.x + pa.y * wa.y + pa.z * wa.z + pa.w * wa.w
                    + pb.x * wb.x + pb.y * wb.y + pb.z * wb.z + pb.w * wb.w;
            if (lane == 0) a += pr[512] * wrow[512] + pr[513] * wrow[513];
            a += __shfl_xor(a, 1); a += __shfl_xor(a, 2); a += __shfl_xor(a, 4);
            a += __shfl_xor(a, 8); a += __shfl_xor(a, 16); a += __shfl_xor(a, 32);
            if (lane == 0) {
                a += fc1b[u];
                a = a * (gf1[u] * bninv) + bf1[u];
                z1[u] = fmaxf(a, 0.f);
            }
        }
    }
    __syncthreads();

    {
        int u = t & 31, sp = t >> 5;
        float b = 0.f;
#pragma unroll
        for (int k = sp * 8; k < sp * 8 + 8; ++k) b += z1[k] * fc2w[k * 32 + u];
        zz2[sp][u] = b;
    }
    __syncthreads();
    if (t < 32) {
        float b = 0.f;
#pragma unroll
        for (int sp = 0; sp < 8; ++sp) b += zz2[sp][t];
        b += fc2b[t];
        b = b * (gf2[t] * bninv) + bf2[t];
        z2[t] = fmaxf(b, 0.f);
    }
    __syncthreads();

    if (t < 2) {
        float c = 0.f;
#pragma unroll
        for (int k = 0; k < 32; ++k) c += z2[k] * fc3w[k * 2 + t];
        out[g * 2 + t] = c + fc3b[t];
    }
}

// ---------------- launch ----------------

extern "C" void kernel_launch(void* const* d_in, const int* in_sizes, int n_in,
                              void* d_out, int out_size, void* d_ws, size_t ws_size,
                              hipStream_t stream) {
    const float* x    = (const float*)d_in[0];
    const int*   ei   = (const int*)d_in[1];
    const int*   batch= (const int*)d_in[2];
    const float* gsz  = (const float*)d_in[3];
    const float* W1   = (const float*)d_in[4];
    const float* as1  = (const float*)d_in[5];
    const float* ad1  = (const float*)d_in[6];
    const float* b1   = (const float*)d_in[7];
    const float* g1   = (const float*)d_in[8];
    const float* be1  = (const float*)d_in[9];
    const float* W2   = (const float*)d_in[10];
    const float* as2  = (const float*)d_in[11];
    const float* ad2  = (const float*)d_in[12];
    const float* b2   = (const float*)d_in[13];
    const float* g2   = (const float*)d_in[14];
    const float* be2  = (const float*)d_in[15];
    const float* fc1w = (const float*)d_in[16];
    const float* fc1b = (const float*)d_in[17];
    const float* gf1  = (const float*)d_in[18];
    const float* bf1  = (const float*)d_in[19];
    const float* fc2w = (const float*)d_in[20];
    const float* fc2b = (const float*)d_in[21];
    const float* gf2  = (const float*)d_in[22];
    const float* bf2  = (const float*)d_in[23];
    const float* fc3w = (const float*)d_in[24];
    const float* fc3b = (const float*)d_in[25];
    float* out = (float*)d_out;

    char* w = (char*)d_ws;
    _Float16* h_half   = (_Float16*)w; w += (size_t)N_NODES * HC * 2;   // 10.24 MB
    _Float16* act_half = (_Float16*)w; w += (size_t)N_NODES * HC * 2;   // 10.24 MB
    _Float16* act2_half= (_Float16*)w; w += (size_t)N_NODES * HC * 2;   // 10.24 MB
    _Float16* Wt       = (_Float16*)w; w += (size_t)HC * HC * 2;        // 128 KB
    _Float16* W1t      = (_Float16*)w; w += (size_t)HC * 64 * 2;        // 32 KB
    _Float16* xpad     = (_Float16*)w; w += (size_t)NPAD * 64 * 2;      // 2.56 MB
    float* fc1wT       = (float*)w;    w += (size_t)64 * 520 * 4;       // 133 KB
    float* ssrc        = (float*)w;    w += (size_t)N_NODES * NH * 4;
    float* sdst        = (float*)w;    w += (size_t)N_NODES * NH * 4;
    int* row_ptr  = (int*)w;   w += (size_t)(N_NODES + 1) * 4;
    int* cursor   = (int*)w;   w += (size_t)N_NODES * 4;
    // cnt, gstart, gend contiguous -> single memset
    int* cnt      = (int*)w;   w += (size_t)N_NODES * 4;
    int* gstart   = (int*)w;   w += 64 * 4;
    int* gend     = (int*)w;   w += 64 * 4;
    int* colidx   = (int*)w;   w += (size_t)(E_EDGES + N_NODES) * 4;
    int* partial  = (int*)w;   w += 64 * 4;

    // pool partials alias h_half (dead after gat_agg#2)
    float* psum = (float*)h_half;
    float* pmax = psum + (size_t)NG * PCHUNK * HC;

    hipMemsetAsync(cnt, 0, (size_t)(N_NODES + 128) * 4, stream);  // cnt + gstart + gend

    prep<<<2164, 256, 0, stream>>>(W2, Wt, fc1w, fc1wT, batch, gstart, gend, W1, W1t, x, xpad, ei, cnt);
    scanA<<<40, 512, 0, stream>>>(cnt, partial);
    scanC<<<40, 512, 0, stream>>>(cnt, partial, row_ptr, cursor, colidx);
    fill_csr<<<1250, 256, 0, stream>>>(ei, cursor, colidx);

    gemm41h<<<626, 256, 0, stream>>>(xpad, W1t, as1, ad1, h_half, ssrc, sdst);
    gat_agg<<<5000, 256, 0, stream>>>(row_ptr, colidx, ssrc, sdst, h_half, b1, g1, be1, act_half);

    gemm256h<<<626, 256, 0, stream>>>(act_half, Wt, as2, ad2, h_half, ssrc, sdst);
    gat_agg<<<5000, 256, 0, stream>>>(row_ptr, colidx, ssrc, sdst, h_half, b2, g2, be2, act2_half);

    pool_partial<<<NG * PCHUNK, 256, 0, stream>>>(act2_half, gstart, gend, psum, pmax);
    mlp<<<NG, 256, 0, stream>>>(psum, pmax, gstart, gend, gsz,
                                fc1wT, fc1b, gf1, bf1, fc2w, fc2b, gf2, bf2, fc3w, fc3b, out);
}

// Round 16
// 151.138 us; speedup vs baseline: 1.1050x; 1.0627x over previous
//
#include <hip/hip_runtime.h>
#include <hip/hip_bf16.h>

#define N_NODES 20000
#define E_EDGES 320000
#define NH 8
#define NC 32
#define HC 256
#define FIN 41
#define NG 64
#define PCHUNK 16
#define NPAD 20032

typedef _Float16 f16x4 __attribute__((ext_vector_type(4)));
typedef _Float16 f16x8 __attribute__((ext_vector_type(8)));
typedef float f32x4v __attribute__((ext_vector_type(4)));

// ---------------- CSR build ----------------
// cnt[] holds EDGE counts only (zeroed by memset); row size = cnt[n] + 1 (self loop).

__global__ __launch_bounds__(512) void scanA(const int* __restrict__ cnt, int* partial) {
    __shared__ int red[512];
    int n = blockIdx.x * 512 + threadIdx.x;
    int v = (n < N_NODES) ? cnt[n] + 1 : 0;
    red[threadIdx.x] = v; __syncthreads();
    for (int off = 256; off > 0; off >>= 1) {
        if (threadIdx.x < off) red[threadIdx.x] += red[threadIdx.x + off];
        __syncthreads();
    }
    if (threadIdx.x == 0) partial[blockIdx.x] = red[0];
}

// scanC with inlined cross-block prefix (first wave shfl-scans the 40 partials)
__global__ __launch_bounds__(512) void scanC(const int* __restrict__ cnt, const int* __restrict__ partial,
                                             int* row_ptr, int* cursor, int* colidx) {
    __shared__ int buf[512];
    __shared__ int pbase;
    int t = threadIdx.x;
    if (t < 64) {
        int v = (t < 40) ? partial[t] : 0;
        int own = v;
        for (int off = 1; off < 64; off <<= 1) {
            int y = __shfl_up(v, off);
            if (t >= off) v += y;
        }
        if (t == (int)blockIdx.x) pbase = v - own;  // exclusive prefix at blockIdx.x
    }
    int n = blockIdx.x * 512 + t;
    int v = (n < N_NODES) ? cnt[n] + 1 : 0;
    int x = v;
    buf[t] = x; __syncthreads();
    for (int off = 1; off < 512; off <<= 1) {
        int y = (t >= off) ? buf[t - off] : 0;
        __syncthreads();
        x += y; buf[t] = x; __syncthreads();
    }
    int excl = pbase + x - v;
    if (n < N_NODES) {
        row_ptr[n] = excl;
        cursor[n] = excl + 1;     // self loop occupies slot 0
        colidx[excl] = n;         // self loop
    }
    if (n == 0) row_ptr[N_NODES] = E_EDGES + N_NODES;
}

// ---------------- prep (+ fused hist) ----------------
// blocks 0..15:     W2 -> fp16 col-major Wt[256][256]
// blocks 16..144:   fc1w -> fc1wT[64][520]
// blocks 145..223:  graph_ranges
// blocks 224..287:  W1 [41][256] -> fp16 col-major W1t[256][64] (zero-padded K)
// blocks 288..913:  x [20000][41] -> fp16 xpad[20032][64] (zero-padded)
// blocks 914..2163: hist (dst-degree histogram; cnt pre-zeroed by memset)

__global__ __launch_bounds__(256) void prep(const float* __restrict__ W, _Float16* __restrict__ Wt,
                                            const float* __restrict__ fc1w, float* __restrict__ fc1wT,
                                            const int* __restrict__ batch, int* gstart, int* gend,
                                            const float* __restrict__ W1, _Float16* __restrict__ W1t,
                                            const float* __restrict__ x, _Float16* __restrict__ xpad,
                                            const int* __restrict__ ei, int* cnt) {
    __shared__ float tile[64][65];
    int b = blockIdx.x;
    int t = threadIdx.x;
    if (b < 16) {
        int tr = (b >> 2) * 64;
        int tc = (b & 3) * 64;
        int rr = t >> 6, cc = t & 63;
#pragma unroll
        for (int j = 0; j < 16; ++j) {
            int row = j * 4 + rr;
            tile[row][cc] = W[(size_t)(tr + row) * 256 + tc + cc];
        }
        __syncthreads();
#pragma unroll
        for (int j = 0; j < 16; ++j) {
            int row = j * 4 + rr;
            Wt[(size_t)(tc + row) * 256 + tr + cc] = (_Float16)tile[cc][row];
        }
    } else if (b < 145) {
        int id = (b - 16) * 256 + t;
        if (id < 64 * 514) {
            int u = id / 514, kk = id - u * 514;
            fc1wT[u * 520 + kk] = fc1w[kk * 64 + u];
        }
    } else if (b < 224) {
        int n = (b - 145) * 256 + t;
        if (n < N_NODES) {
            int bb = batch[n];
            if (n == 0) gstart[bb] = 0;
            else {
                int pb = batch[n - 1];
                if (pb != bb) { gstart[bb] = n; gend[pb] = n; }
            }
            if (n == N_NODES - 1) gend[bb] = N_NODES;
        }
    } else if (b < 288) {
        int id = (b - 224) * 256 + t;       // 16384 = 256 cols x 64 K
        int n = id >> 6, k = id & 63;
        W1t[id] = (k < FIN) ? (_Float16)W1[k * 256 + n] : (_Float16)0.f;
    } else if (b < 914) {
        int row = (b - 288) * 32 + (t >> 3);
        int c8 = (t & 7) * 8;
        f16x8 v;
#pragma unroll
        for (int j = 0; j < 8; ++j) {
            int c = c8 + j;
            float f = (row < N_NODES && c < FIN) ? x[(size_t)row * FIN + c] : 0.f;
            v[j] = (_Float16)f;
        }
        if (row < NPAD) *(f16x8*)(xpad + (size_t)row * 64 + c8) = v;
    } else {
        int e = (b - 914) * 256 + t;
        if (e < E_EDGES) atomicAdd(&cnt[ei[E_EDGES + e]], 1);
    }
}

// ---------------- GEMM K=256 via MFMA fp16 (16x16x32), B-in-LDS, 64x128 blocks ----------------

__global__ __launch_bounds__(256) void gemm256h(const _Float16* __restrict__ Xh,
                                                const _Float16* __restrict__ Wt,
                                                const float* __restrict__ a_src,
                                                const float* __restrict__ a_dst,
                                                _Float16* __restrict__ Hh,
                                                _Float16* __restrict__ ssrc,
                                                _Float16* __restrict__ sdst) {
    __shared__ _Float16 bs[128 * 272];          // 69.6 KB; reused as hs[64*136] after compute
    int row0 = (blockIdx.x >> 1) * 64;
    int half = blockIdx.x & 1;
    int c0 = half * 128;
    int tid = threadIdx.x;
    int lane = tid & 63;
    int v = tid >> 6;
    int r16 = lane & 15;
    int kseg = lane >> 4;

#pragma unroll
    for (int i = 0; i < 16; ++i) {
        int chunk = i * 256 + tid;
        int c = chunk >> 5;
        int k = (chunk & 31) * 8;
        f16x8 xv = *(const f16x8*)(Wt + (size_t)(c0 + c) * 256 + k);
        *(f16x8*)(&bs[c * 272 + k]) = xv;
    }

    int arow = row0 + v * 16 + r16;
    const _Float16* XA = Xh + (size_t)arow * 256 + kseg * 8;
    f16x8 af[8];
#pragma unroll
    for (int s = 0; s < 8; ++s) af[s] = *(const f16x8*)(XA + s * 32);

    __syncthreads();

    f32x4v acc[8];
#pragma unroll
    for (int tn = 0; tn < 8; ++tn) acc[tn] = (f32x4v){0.f, 0.f, 0.f, 0.f};

#pragma unroll
    for (int tn = 0; tn < 8; ++tn) {
        f16x8 bf[8];
#pragma unroll
        for (int s = 0; s < 8; ++s)
            bf[s] = *(const f16x8*)(&bs[(tn * 16 + r16) * 272 + kseg * 8 + s * 32]);
#pragma unroll
        for (int s = 0; s < 8; ++s)
            acc[tn] = __builtin_amdgcn_mfma_f32_16x16x32_f16(af[s], bf[s], acc[tn], 0, 0, 0);
    }

#pragma unroll
    for (int hh = 0; hh < 4; ++hh) {
        float as0 = a_src[c0 + hh * 32 + r16], as1 = a_src[c0 + hh * 32 + 16 + r16];
        float ad0 = a_dst[c0 + hh * 32 + r16], ad1 = a_dst[c0 + hh * 32 + 16 + r16];
#pragma unroll
        for (int r = 0; r < 4; ++r) {
            float p = acc[2 * hh][r] * as0 + acc[2 * hh + 1][r] * as1;
            float q = acc[2 * hh][r] * ad0 + acc[2 * hh + 1][r] * ad1;
            p += __shfl_xor(p, 1); q += __shfl_xor(q, 1);
            p += __shfl_xor(p, 2); q += __shfl_xor(q, 2);
            p += __shfl_xor(p, 4); q += __shfl_xor(q, 4);
            p += __shfl_xor(p, 8); q += __shfl_xor(q, 8);
            int row = row0 + v * 16 + kseg * 4 + r;
            if (r16 == 0 && row < N_NODES) {
                ssrc[row * NH + half * 4 + hh] = (_Float16)p;
                sdst[row * NH + half * 4 + hh] = (_Float16)q;
            }
        }
    }

    __syncthreads();
    _Float16* hs = bs;
#pragma unroll
    for (int tn = 0; tn < 8; ++tn)
#pragma unroll
        for (int r = 0; r < 4; ++r)
            hs[(v * 16 + kseg * 4 + r) * 136 + tn * 16 + r16] = (_Float16)acc[tn][r];
    __syncthreads();
#pragma unroll
    for (int i = 0; i < 4; ++i) {
        int idx = i * 256 + tid;
        int row = idx >> 4;
        int c8 = (idx & 15) * 8;
        if (row0 + row < N_NODES) {
            f16x8 xv = *(const f16x8*)&hs[row * 136 + c8];
            *(f16x8*)(Hh + (size_t)(row0 + row) * 256 + c0 + c8) = xv;
        }
    }
}

// ---------------- GEMM K=64(41 padded) MFMA + fused fill_csr (grid-partitioned) ----------------
// blocks 0..625: gemm41h (64x128 tiles); blocks 626..1875: fill_csr edges.

__global__ __launch_bounds__(256) void gemm41_fill(const _Float16* __restrict__ Xh,
                                                   const _Float16* __restrict__ W1t,
                                                   const float* __restrict__ a_src,
                                                   const float* __restrict__ a_dst,
                                                   _Float16* __restrict__ Hh,
                                                   _Float16* __restrict__ ssrc,
                                                   _Float16* __restrict__ sdst,
                                                   const int* __restrict__ ei,
                                                   int* cursor, int* colidx) {
    __shared__ _Float16 bs[128 * 72];
    __shared__ _Float16 hs[64 * 136];
    int b = blockIdx.x;
    int tid = threadIdx.x;

    if (b >= 626) {
        int e = (b - 626) * 256 + tid;
        if (e < E_EDGES) {
            int d = ei[E_EDGES + e];
            int s = ei[e];
            int pos = atomicAdd(&cursor[d], 1);
            colidx[pos] = s;
        }
        return;
    }

    int row0 = (b >> 1) * 64;
    int half = b & 1;
    int c0 = half * 128;
    int lane = tid & 63;
    int v = tid >> 6;
    int r16 = lane & 15;
    int kseg = lane >> 4;

#pragma unroll
    for (int i = 0; i < 4; ++i) {
        int chunk = i * 256 + tid;
        int c = chunk >> 3;
        int k = (chunk & 7) * 8;
        f16x8 xv = *(const f16x8*)(W1t + (size_t)(c0 + c) * 64 + k);
        *(f16x8*)(&bs[c * 72 + k]) = xv;
    }

    int arow = row0 + v * 16 + r16;
    const _Float16* XA = Xh + (size_t)arow * 64 + kseg * 8;
    f16x8 af[2];
    af[0] = *(const f16x8*)(XA);
    af[1] = *(const f16x8*)(XA + 32);

    __syncthreads();

    f32x4v acc[8];
#pragma unroll
    for (int tn = 0; tn < 8; ++tn) acc[tn] = (f32x4v){0.f, 0.f, 0.f, 0.f};

#pragma unroll
    for (int tn = 0; tn < 8; ++tn) {
        f16x8 bf0 = *(const f16x8*)(&bs[(tn * 16 + r16) * 72 + kseg * 8]);
        f16x8 bf1 = *(const f16x8*)(&bs[(tn * 16 + r16) * 72 + kseg * 8 + 32]);
        acc[tn] = __builtin_amdgcn_mfma_f32_16x16x32_f16(af[0], bf0, acc[tn], 0, 0, 0);
        acc[tn] = __builtin_amdgcn_mfma_f32_16x16x32_f16(af[1], bf1, acc[tn], 0, 0, 0);
    }

#pragma unroll
    for (int hh = 0; hh < 4; ++hh) {
        float as0 = a_src[c0 + hh * 32 + r16], as1 = a_src[c0 + hh * 32 + 16 + r16];
        float ad0 = a_dst[c0 + hh * 32 + r16], ad1 = a_dst[c0 + hh * 32 + 16 + r16];
#pragma unroll
        for (int r = 0; r < 4; ++r) {
            float p = acc[2 * hh][r] * as0 + acc[2 * hh + 1][r] * as1;
            float q = acc[2 * hh][r] * ad0 + acc[2 * hh + 1][r] * ad1;
            p += __shfl_xor(p, 1); q += __shfl_xor(q, 1);
            p += __shfl_xor(p, 2); q += __shfl_xor(q, 2);
            p += __shfl_xor(p, 4); q += __shfl_xor(q, 4);
            p += __shfl_xor(p, 8); q += __shfl_xor(q, 8);
            int row = row0 + v * 16 + kseg * 4 + r;
            if (r16 == 0 && row < N_NODES) {
                ssrc[row * NH + half * 4 + hh] = (_Float16)p;
                sdst[row * NH + half * 4 + hh] = (_Float16)q;
            }
        }
    }

    __syncthreads();
#pragma unroll
    for (int tn = 0; tn < 8; ++tn)
#pragma unroll
        for (int r = 0; r < 4; ++r)
            hs[(v * 16 + kseg * 4 + r) * 136 + tn * 16 + r16] = (_Float16)acc[tn][r];
    __syncthreads();
#pragma unroll
    for (int i = 0; i < 4; ++i) {
        int idx = i * 256 + tid;
        int row = idx >> 4;
        int c8 = (idx & 15) * 8;
        if (row0 + row < N_NODES) {
            f16x8 xv = *(const f16x8*)&hs[row * 136 + c8];
            *(f16x8*)(Hh + (size_t)(row0 + row) * 256 + c0 + c8) = xv;
        }
    }
}

// ---------------- fused GAT aggregation + bias + BN(eval) + ELU ----------------
// Single pass (softmax shift-invariance; scores O(1) -> exp safe in fp32). fp16 scores.

__global__ __launch_bounds__(256) void gat_agg(const int* __restrict__ row_ptr,
                                               const int* __restrict__ colidx,
                                               const _Float16* __restrict__ ssrc,
                                               const _Float16* __restrict__ sdst,
                                               const _Float16* __restrict__ h,
                                               const float* __restrict__ bias,
                                               const float* __restrict__ gamma,
                                               const float* __restrict__ beta,
                                               _Float16* __restrict__ outh) {
    int wave = (blockIdx.x * blockDim.x + threadIdx.x) >> 6;
    int lane = threadIdx.x & 63;
    if (wave >= N_NODES) return;
    int n = wave;
    int beg = row_ptr[n], end = row_ptr[n + 1];
    int deg = end - beg;

    int hd = lane >> 3;
    float sd = (float)sdst[n * NH + hd];
    int c = lane * 4;
    float acc0 = 0.f, acc1 = 0.f, acc2 = 0.f, acc3 = 0.f, denom = 0.f;

    int i = 0;
    for (; i + 8 <= deg; i += 8) {
        int sidx[8];
#pragma unroll
        for (int j = 0; j < 8; ++j) sidx[j] = colidx[beg + i + j];
        float wv[8];
#pragma unroll
        for (int j = 0; j < 8; ++j) {
            float v = (float)ssrc[sidx[j] * NH + hd] + sd;
            v = (v >= 0.f) ? v : 0.2f * v;
            wv[j] = __expf(v);
        }
        f16x4 hv[8];
#pragma unroll
        for (int j = 0; j < 8; ++j) hv[j] = *reinterpret_cast<const f16x4*>(h + (size_t)sidx[j] * HC + c);
#pragma unroll
        for (int j = 0; j < 8; ++j) {
            denom += wv[j];
            acc0 += wv[j] * (float)hv[j][0];
            acc1 += wv[j] * (float)hv[j][1];
            acc2 += wv[j] * (float)hv[j][2];
            acc3 += wv[j] * (float)hv[j][3];
        }
    }
    for (; i < deg; ++i) {
        int s = colidx[beg + i];
        float v = (float)ssrc[s * NH + hd] + sd;
        v = (v >= 0.f) ? v : 0.2f * v;
        float wgt = __expf(v);
        denom += wgt;
        const f16x4 hv = *reinterpret_cast<const f16x4*>(h + (size_t)s * HC + c);
        acc0 += wgt * (float)hv[0]; acc1 += wgt * (float)hv[1];
        acc2 += wgt * (float)hv[2]; acc3 += wgt * (float)hv[3];
    }
    float inv = 1.0f / denom;
    const float bninv = 0.99999500003749981f;  // 1/sqrt(1+1e-5)
    float vals[4] = {acc0, acc1, acc2, acc3};
    f16x4 o;
#pragma unroll
    for (int j = 0; j < 4; ++j) {
        float v = vals[j] * inv + bias[c + j];
        v = v * (gamma[c + j] * bninv) + beta[c + j];
        v = (v > 0.f) ? v : (__expf(v) - 1.0f);
        o[j] = (_Float16)v;
    }
    *(f16x4*)(outh + (size_t)n * HC + c) = o;
}

// ---------------- pooling (vectorized: 4 waves x f16x4/lane, LDS 4-way reduce) ----------------

__global__ __launch_bounds__(256) void pool_partial(const _Float16* __restrict__ h,
                                                    const int* __restrict__ gstart,
                                                    const int* __restrict__ gend,
                                                    float* __restrict__ psum,
                                                    float* __restrict__ pmax) {
    __shared__ float ssm[4][256];
    __shared__ float smx[4][256];
    int g = blockIdx.x >> 4;
    int c = blockIdx.x & (PCHUNK - 1);
    int t = threadIdx.x;
    int wv = t >> 6;
    int lane = t & 63;
    int c4 = lane * 4;
    int s = gstart[g], e = gend[g];
    int len = e - s;
    int n0 = s + (int)(((long long)len * c) / PCHUNK);
    int n1 = s + (int)(((long long)len * (c + 1)) / PCHUNK);
    float s0 = 0.f, s1 = 0.f, s2 = 0.f, s3 = 0.f;
    float m0 = -3.0e38f, m1 = -3.0e38f, m2 = -3.0e38f, m3 = -3.0e38f;
    for (int n = n0 + wv; n < n1; n += 4) {
        f16x4 v = *(const f16x4*)(h + (size_t)n * HC + c4);
        float f0 = (float)v[0], f1 = (float)v[1], f2 = (float)v[2], f3 = (float)v[3];
        s0 += f0; s1 += f1; s2 += f2; s3 += f3;
        m0 = fmaxf(m0, f0); m1 = fmaxf(m1, f1); m2 = fmaxf(m2, f2); m3 = fmaxf(m3, f3);
    }
    ssm[wv][c4] = s0; ssm[wv][c4 + 1] = s1; ssm[wv][c4 + 2] = s2; ssm[wv][c4 + 3] = s3;
    smx[wv][c4] = m0; smx[wv][c4 + 1] = m1; smx[wv][c4 + 2] = m2; smx[wv][c4 + 3] = m3;
    __syncthreads();
    float fs = ssm[0][t] + ssm[1][t] + ssm[2][t] + ssm[3][t];
    float fm = fmaxf(fmaxf(smx[0][t], smx[1][t]), fmaxf(smx[2][t], smx[3][t]));
    size_t base = (size_t)(g * PCHUNK + c) * HC + t;
    psum[base] = fs;
    pmax[base] = fm;
}

// ---------------- MLP head (fused pool-finalize + 3 FC layers) ----------------

__global__ __launch_bounds__(256) void mlp(const float* __restrict__ psum,
                                           const float* __restrict__ pmax,
                                           const int* __restrict__ gstart,
                                           const int* __restrict__ gend,
                                           const float* __restrict__ gsz,
                                           const float* __restrict__ fc1wT, const float* __restrict__ fc1b,
                                           const float* __restrict__ gf1, const float* __restrict__ bf1,
                                           const float* __restrict__ fc2w, const float* __restrict__ fc2b,
                                           const float* __restrict__ gf2, const float* __restrict__ bf2,
                                           const float* __restrict__ fc3w, const float* __restrict__ fc3b,
                                           float* __restrict__ out) {
    __shared__ __align__(16) float pr[514];
    __shared__ float z1[64];
    __shared__ float zz2[8][32];
    __shared__ float z2[32];
    int g = blockIdx.x;
    int t = threadIdx.x;
    const float bninv = 0.99999500003749981f;

    {
        float s = 0.f, m = -3.0e38f;
#pragma unroll
        for (int c = 0; c < PCHUNK; ++c) {
            s += psum[(size_t)(g * PCHUNK + c) * HC + t];
            m = fmaxf(m, pmax[(size_t)(g * PCHUNK + c) * HC + t]);
        }
        float cnt = (float)(gend[g] - gstart[g]);
        pr[t] = s / fmaxf(cnt, 1.f);
        pr[256 + t] = m;
        if (t < 2) pr[512 + t] = gsz[g * 2 + t];
    }
    __syncthreads();

    {
        int wv = t >> 6, lane = t & 63;
        float4 pa = *reinterpret_cast<const float4*>(&pr[lane * 8]);
        float4 pb = *reinterpret_cast<const float4*>(&pr[lane * 8 + 4]);
#pragma unroll 4
        for (int i = 0; i < 16; ++i) {
            int u = wv * 16 + i;
            const float* wrow = fc1wT + u * 520;
            float4 wa = *reinterpret_cast<const float4*>(wrow + lane * 8);
            float4 wb = *reinterpret_cast<const float4*>(wrow + lane * 8 + 4);
            float a = pa.x * wa.x + pa.y * wa.y + pa.z * wa.z + pa.w * wa.w
                    + pb.x * wb.x + pb.y * wb.y + pb.z * wb.z + pb.w * wb.w;
            if (lane == 0) a += pr[512] * wrow[512] + pr[513] * wrow[513];
            a += __shfl_xor(a, 1); a += __shfl_xor(a, 2); a += __shfl_xor(a, 4);
            a += __shfl_xor(a, 8); a += __shfl_xor(a, 16); a += __shfl_xor(a, 32);
            if (lane == 0) {
                a += fc1b[u];
                a = a * (gf1[u] * bninv) + bf1[u];
                z1[u] = fmaxf(a, 0.f);
            }
        }
    }
    __syncthreads();

    {
        int u = t & 31, sp = t >> 5;
        float b = 0.f;
#pragma unroll
        for (int k = sp * 8; k < sp * 8 + 8; ++k) b += z1[k] * fc2w[k * 32 + u];
        zz2[sp][u] = b;
    }
    __syncthreads();
    if (t < 32) {
        float b = 0.f;
#pragma unroll
        for (int sp = 0; sp < 8; ++sp) b += zz2[sp][t];
        b += fc2b[t];
        b = b * (gf2[t] * bninv) + bf2[t];
        z2[t] = fmaxf(b, 0.f);
    }
    __syncthreads();

    if (t < 2) {
        float c = 0.f;
#pragma unroll
        for (int k = 0; k < 32; ++k) c += z2[k] * fc3w[k * 2 + t];
        out[g * 2 + t] = c + fc3b[t];
    }
}

// ---------------- launch ----------------

extern "C" void kernel_launch(void* const* d_in, const int* in_sizes, int n_in,
                              void* d_out, int out_size, void* d_ws, size_t ws_size,
                              hipStream_t stream) {
    const float* x    = (const float*)d_in[0];
    const int*   ei   = (const int*)d_in[1];
    const int*   batch= (const int*)d_in[2];
    const float* gsz  = (const float*)d_in[3];
    const float* W1   = (const float*)d_in[4];
    const float* as1  = (const float*)d_in[5];
    const float* ad1  = (const float*)d_in[6];
    const float* b1   = (const float*)d_in[7];
    const float* g1   = (const float*)d_in[8];
    const float* be1  = (const float*)d_in[9];
    const float* W2   = (const float*)d_in[10];
    const float* as2  = (const float*)d_in[11];
    const float* ad2  = (const float*)d_in[12];
    const float* b2   = (const float*)d_in[13];
    const float* g2   = (const float*)d_in[14];
    const float* be2  = (const float*)d_in[15];
    const float* fc1w = (const float*)d_in[16];
    const float* fc1b = (const float*)d_in[17];
    const float* gf1  = (const float*)d_in[18];
    const float* bf1  = (const float*)d_in[19];
    const float* fc2w = (const float*)d_in[20];
    const float* fc2b = (const float*)d_in[21];
    const float* gf2  = (const float*)d_in[22];
    const float* bf2  = (const float*)d_in[23];
    const float* fc3w = (const float*)d_in[24];
    const float* fc3b = (const float*)d_in[25];
    float* out = (float*)d_out;

    char* w = (char*)d_ws;
    _Float16* h_half   = (_Float16*)w; w += (size_t)N_NODES * HC * 2;   // 10.24 MB
    _Float16* act_half = (_Float16*)w; w += (size_t)N_NODES * HC * 2;   // 10.24 MB
    _Float16* act2_half= (_Float16*)w; w += (size_t)N_NODES * HC * 2;   // 10.24 MB
    _Float16* Wt       = (_Float16*)w; w += (size_t)HC * HC * 2;        // 128 KB
    _Float16* W1t      = (_Float16*)w; w += (size_t)HC * 64 * 2;        // 32 KB
    _Float16* xpad     = (_Float16*)w; w += (size_t)NPAD * 64 * 2;      // 2.56 MB
    float* fc1wT       = (float*)w;    w += (size_t)64 * 520 * 4;       // 133 KB
    _Float16* ssrc     = (_Float16*)w; w += (size_t)N_NODES * NH * 2;
    _Float16* sdst     = (_Float16*)w; w += (size_t)N_NODES * NH * 2;
    int* row_ptr  = (int*)w;   w += (size_t)(N_NODES + 1) * 4;
    int* cursor   = (int*)w;   w += (size_t)N_NODES * 4;
    // cnt, gstart, gend contiguous -> single memset
    int* cnt      = (int*)w;   w += (size_t)N_NODES * 4;
    int* gstart   = (int*)w;   w += 64 * 4;
    int* gend     = (int*)w;   w += 64 * 4;
    int* colidx   = (int*)w;   w += (size_t)(E_EDGES + N_NODES) * 4;
    int* partial  = (int*)w;   w += 64 * 4;

    // pool partials alias h_half (dead after gat_agg#2)
    float* psum = (float*)h_half;
    float* pmax = psum + (size_t)NG * PCHUNK * HC;

    hipMemsetAsync(cnt, 0, (size_t)(N_NODES + 128) * 4, stream);  // cnt + gstart + gend

    prep<<<2164, 256, 0, stream>>>(W2, Wt, fc1w, fc1wT, batch, gstart, gend, W1, W1t, x, xpad, ei, cnt);
    scanA<<<40, 512, 0, stream>>>(cnt, partial);
    scanC<<<40, 512, 0, stream>>>(cnt, partial, row_ptr, cursor, colidx);

    gemm41_fill<<<1876, 256, 0, stream>>>(xpad, W1t, as1, ad1, h_half, ssrc, sdst, ei, cursor, colidx);
    gat_agg<<<5000, 256, 0, stream>>>(row_ptr, colidx, ssrc, sdst, h_half, b1, g1, be1, act_half);

    gemm256h<<<626, 256, 0, stream>>>(act_half, Wt, as2, ad2, h_half, ssrc, sdst);
    gat_agg<<<5000, 256, 0, stream>>>(row_ptr, colidx, ssrc, sdst, h_half, b2, g2, be2, act2_half);

    pool_partial<<<NG * PCHUNK, 256, 0, stream>>>(act2_half, gstart, gend, psum, pmax);
    mlp<<<NG, 256, 0, stream>>>(psum, pmax, gstart, gend, gsz,
                                fc1wT, fc1b, gf1, bf1, fc2w, fc2b, gf2, bf2, fc3w, fc3b, out);
}